// Round 3
// baseline (2803.113 us; speedup 1.0000x reference)
//
#include <hip/hip_runtime.h>
#include <math.h>

// ---------------------------------------------------------------------------
// SelfposOnlyVec: BN->Lin->ReLU chain (width 16) with 2 residual blocks,
// concat with 8-entry embedding, classify to 64 outputs. N = 2,000,000.
//
// Training-mode BN => batch stats over intermediates => multi-pass:
//   stats0(pos) -> fold0 -> stats1(h) -> fold1 -> ... -> stats4(y3) -> fold4
//   -> final (recompute h3, classify, 512MB coalesced write)
//
// R2/R3 (counters R1: k_stats 567us each, VALUBusy 89%, HBM 0.2% -> compute
// pathology: per-row global weight reloads, 28x over the 20us FMA floor):
//   * Folded params staged to LDS once per block; weight reads are explicit
//     float4 (ds_read_b128) wave-uniform broadcasts (conflict-free).
//   * RB rows batched per thread (RB=4 shallow, RB=2 deep): each weight read
//     amortizes over RB FMAs; RB independent FMA chains cover fma latency.
//   * k_stats: unmasked accumulate fast path (N % RB == 0 in practice).
//   * k_final: two-phase LDS tile (R1) — phase 1 recomputes h3 per thread,
//     phase 2 maps 16 lanes per row -> wave stores 1 KB contiguous.
//     Embedding classifier table computed in-block (k_table removed).
// ---------------------------------------------------------------------------

#define WG 256
#define GRID_STATS 1024
#define GRID_FINAL 2048
#define NPARAMS 1136   // PW1..PB5 region staged to LDS
#define TROWS 512      // k_final tile rows

// ws layout (floats)
#define PARTIALS_OFF 0                    // GRID_STATS*32 floats
#define PARAMS_OFF   (GRID_STATS * 32)    // folded params block
// offsets relative to params base P (all float4-aligned where needed)
#define PW1 0      // [16][2]
#define PB1 32     // [16]
#define PW2 48     // [16][16]
#define PB2 304
#define PW3 320
#define PB3 576
#define PW4 592
#define PB4 848
#define PW5 864
#define PB5 1120
// params end at 1136 floats; total ws use = (32768+1136)*4 ~ 136 KB

// Batched 16->16 linear+relu, weights from LDS via explicit float4 reads
// (wave-uniform broadcast, conflict-free; guarantees ds_read_b128).
template <int RB>
__device__ __forceinline__ void lin_relu16_b(const float* WL, int wOff, int bOff,
                                             const float x[RB][16], float y[RB][16]) {
  #pragma unroll
  for (int o = 0; o < 16; ++o) {
    const float4* wr = (const float4*)(WL + wOff + o * 16);
    const float4 wa = wr[0], wb = wr[1], wcc = wr[2], wd = wr[3];
    const float bo = WL[bOff + o];
    #pragma unroll
    for (int r = 0; r < RB; ++r) {
      float a = fmaf(wa.x, x[r][0], bo);
      float b = wa.y * x[r][1];
      a = fmaf(wa.z, x[r][2], a);  b = fmaf(wa.w, x[r][3], b);
      a = fmaf(wb.x, x[r][4], a);  b = fmaf(wb.y, x[r][5], b);
      a = fmaf(wb.z, x[r][6], a);  b = fmaf(wb.w, x[r][7], b);
      a = fmaf(wcc.x, x[r][8], a); b = fmaf(wcc.y, x[r][9], b);
      a = fmaf(wcc.z, x[r][10], a); b = fmaf(wcc.w, x[r][11], b);
      a = fmaf(wd.x, x[r][12], a); b = fmaf(wd.y, x[r][13], b);
      a = fmaf(wd.z, x[r][14], a); b = fmaf(wd.w, x[r][15], b);
      y[r][o] = fmaxf(a + b, 0.f);
    }
  }
}

// DEPTH: 0=raw pos (padded to 16), 1=h, 2=y1, 3=h2, 4=y3, 5=h3
template <int DEPTH, int RB>
__device__ __forceinline__ void forward_rows(const float* WL,
                                             const float px[RB], const float py[RB],
                                             float v[RB][16]) {
  if (DEPTH == 0) {
    #pragma unroll
    for (int r = 0; r < RB; ++r) {
      v[r][0] = px[r]; v[r][1] = py[r];
      #pragma unroll
      for (int i = 2; i < 16; ++i) v[r][i] = 0.f;
    }
    return;
  }
  float h[RB][16];
  #pragma unroll
  for (int o = 0; o < 16; ++o) {
    const float2 w01 = ((const float2*)(WL + PW1))[o];
    const float b0 = WL[PB1 + o];
    #pragma unroll
    for (int r = 0; r < RB; ++r)
      h[r][o] = fmaxf(fmaf(w01.x, px[r], fmaf(w01.y, py[r], b0)), 0.f);
  }
  if (DEPTH == 1) {
    #pragma unroll
    for (int r = 0; r < RB; ++r)
      #pragma unroll
      for (int i = 0; i < 16; ++i) v[r][i] = h[r][i];
    return;
  }
  float y[RB][16];
  lin_relu16_b<RB>(WL, PW2, PB2, h, y);      // y1
  if (DEPTH == 2) {
    #pragma unroll
    for (int r = 0; r < RB; ++r)
      #pragma unroll
      for (int i = 0; i < 16; ++i) v[r][i] = y[r][i];
    return;
  }
  float z[RB][16];
  lin_relu16_b<RB>(WL, PW3, PB3, y, z);      // y2
  #pragma unroll
  for (int r = 0; r < RB; ++r)
    #pragma unroll
    for (int o = 0; o < 16; ++o) h[r][o] += z[r][o];   // h2 = h + y2
  if (DEPTH == 3) {
    #pragma unroll
    for (int r = 0; r < RB; ++r)
      #pragma unroll
      for (int i = 0; i < 16; ++i) v[r][i] = h[r][i];
    return;
  }
  lin_relu16_b<RB>(WL, PW4, PB4, h, y);      // y3 (reuse y)
  if (DEPTH == 4) {
    #pragma unroll
    for (int r = 0; r < RB; ++r)
      #pragma unroll
      for (int i = 0; i < 16; ++i) v[r][i] = y[r][i];
    return;
  }
  lin_relu16_b<RB>(WL, PW5, PB5, y, z);      // y4 (reuse z)
  #pragma unroll
  for (int r = 0; r < RB; ++r)
    #pragma unroll
    for (int i = 0; i < 16; ++i) v[r][i] = h[r][i] + z[r][i];  // h3
}

// Per-pass stats: per-thread sums -> wave shuffle reduce -> LDS -> per-block
// partials[block*32 + c] (c<16: sum, c>=16: sumsq). Deterministic, no atomics.
template <int DEPTH, int RB>
__global__ __launch_bounds__(WG) void k_stats(const float* __restrict__ pos, int N,
                                              const float* __restrict__ P,
                                              float* __restrict__ partials) {
  __shared__ alignas(16) float WL[NPARAMS];
  if (DEPTH > 0) {
    for (int i = threadIdx.x; i < NPARAMS; i += WG) WL[i] = P[i];
    __syncthreads();
  }
  constexpr int NC = (DEPTH == 0) ? 2 : 16;  // raw pos is width-2
  float s[16], q[16];
  #pragma unroll
  for (int c = 0; c < 16; ++c) { s[c] = 0.f; q[c] = 0.f; }

  const int stride = GRID_STATS * WG * RB;
  for (int r0 = (blockIdx.x * WG + threadIdx.x) * RB; r0 < N; r0 += stride) {
    const bool full = (r0 + RB <= N);
    float px[RB], py[RB];
    if (full) {
      #pragma unroll
      for (int j = 0; j < RB / 2; ++j) {
        float4 v4 = *(const float4*)(pos + 2 * (r0 + 2 * j));  // rows r0+2j, +1
        px[2 * j] = v4.x;     py[2 * j] = v4.y;
        px[2 * j + 1] = v4.z; py[2 * j + 1] = v4.w;
      }
    } else {
      #pragma unroll
      for (int j = 0; j < RB; ++j) {
        int r = r0 + j;
        px[j] = (r < N) ? pos[2 * r] : 0.f;
        py[j] = (r < N) ? pos[2 * r + 1] : 0.f;
      }
    }
    float v[RB][16];
    forward_rows<DEPTH, RB>(WL, px, py, v);
    if (full) {
      #pragma unroll
      for (int j = 0; j < RB; ++j)
        #pragma unroll
        for (int c = 0; c < NC; ++c) {
          s[c] += v[j][c];
          q[c] = fmaf(v[j][c], v[j][c], q[c]);
        }
    } else {
      #pragma unroll
      for (int j = 0; j < RB; ++j) {
        if (r0 + j < N) {
          #pragma unroll
          for (int c = 0; c < NC; ++c) {
            s[c] += v[j][c];
            q[c] = fmaf(v[j][c], v[j][c], q[c]);
          }
        }
      }
    }
  }

  __shared__ float redS[4][16], redQ[4][16];
  int lane = threadIdx.x & 63, wave = threadIdx.x >> 6;
  #pragma unroll
  for (int c = 0; c < 16; ++c) {
    float vs = s[c], vq = q[c];
    #pragma unroll
    for (int mm = 1; mm < 64; mm <<= 1) {
      vs += __shfl_xor(vs, mm, 64);
      vq += __shfl_xor(vq, mm, 64);
    }
    if (lane == 0) { redS[wave][c] = vs; redQ[wave][c] = vq; }
  }
  __syncthreads();
  if (threadIdx.x < 16) {
    int c = threadIdx.x;
    partials[blockIdx.x * 32 + c]      = redS[0][c] + redS[1][c] + redS[2][c] + redS[3][c];
    partials[blockIdx.x * 32 + 16 + c] = redQ[0][c] + redQ[1][c] + redQ[2][c] + redQ[3][c];
  }
}

// One block: reduce partials -> mean/var -> fold BN into next linear.
// Wf[o][c] = W[o][c]*scale[c]; bf[o] = bias[o] + sum_c W[o][c]*shift[c]
__global__ __launch_bounds__(WG) void k_fold(const float* __restrict__ partials,
                                             const float* __restrict__ gam,
                                             const float* __restrict__ bet,
                                             const float* __restrict__ W,
                                             const float* __restrict__ bias,
                                             int C, int O, float invN,
                                             float* __restrict__ Wf,
                                             float* __restrict__ bf) {
  __shared__ float red[8][32];
  __shared__ float colsum[32];
  __shared__ float scale[16], shift[16];
  int t = threadIdx.x;
  int c = t & 31, grp = t >> 5;
  float acc = 0.f;
  for (int bI = grp; bI < GRID_STATS; bI += 8) acc += partials[bI * 32 + c];
  red[grp][c] = acc;
  __syncthreads();
  if (t < 32) {
    float x = 0.f;
    #pragma unroll
    for (int g2 = 0; g2 < 8; ++g2) x += red[g2][t];
    colsum[t] = x;
  }
  __syncthreads();
  if (t < C) {
    float mean = colsum[t] * invN;
    float var  = colsum[16 + t] * invN - mean * mean;
    float sc   = gam[t] / sqrtf(var + 1e-5f);
    scale[t] = sc;
    shift[t] = bet[t] - mean * sc;
  }
  __syncthreads();
  for (int o = t; o < O; o += WG) {
    float a2 = bias[o];
    for (int cc = 0; cc < C; ++cc) {
      float w = W[o * C + cc];
      Wf[o * C + cc] = w * scale[cc];
      a2 = fmaf(w, shift[cc], a2);
    }
    bf[o] = a2;
  }
}

// Final pass, two-phase per 512-row tile (RB=2 rows/thread in phase 1):
//   phase 1: thread t computes h3(rows base+2t, base+2t+1) -> sh, idx -> sidx
//   phase 2: 16 threads per row (chunk = t&15); each computes 4 outputs
//            from sh + register weights + LDS t2 and stores one float4.
//            Lanes 0..15 cover one row's 256 B -> wave stores 1 KB contiguous.
__global__ __launch_bounds__(WG) void k_final(const float* __restrict__ pos,
                                              const int* __restrict__ idx,
                                              const float* __restrict__ P,
                                              const float* __restrict__ wc,
                                              const float* __restrict__ emb,
                                              const float* __restrict__ bc,
                                              float* __restrict__ out, int N) {
  __shared__ alignas(16) float WL[NPARAMS];
  __shared__ alignas(16) float sh[TROWS][20];  // h3 per row; stride 20 floats
  __shared__ int sidx[TROWS];
  __shared__ float4 st2[128];                  // t2: [pid][chunk] float4 = [8][64] floats

  const int t = threadIdx.x;
  const int chunk = t & 15;
  const int rgrp  = t >> 4;

  for (int i = t; i < NPARAMS; i += WG) WL[i] = P[i];

  // embedding-side classifier table, computed in-block (replaces k_table):
  // t2[p][o] = bc[o] + sum_i emb[p][i] * wc[o][16+i]
  for (int s2 = t; s2 < 512; s2 += WG) {
    int p = s2 >> 6, o = s2 & 63;
    float acc = bc[o];
    #pragma unroll
    for (int i = 0; i < 16; ++i) acc = fmaf(emb[p * 16 + i], wc[o * 32 + 16 + i], acc);
    ((float*)st2)[p * 64 + o] = acc;
  }

  // classifier weights for this thread's 4 output columns (held in VGPRs)
  float4 w4[16];
  #pragma unroll
  for (int i = 0; i < 16; ++i) {
    w4[i].x = wc[(chunk * 4 + 0) * 32 + i];
    w4[i].y = wc[(chunk * 4 + 1) * 32 + i];
    w4[i].z = wc[(chunk * 4 + 2) * 32 + i];
    w4[i].w = wc[(chunk * 4 + 3) * 32 + i];
  }
  __syncthreads();  // WL/st2 ready

  for (int base = blockIdx.x * TROWS; base < N; base += gridDim.x * TROWS) {
    // ---- phase 1: chain recompute (RB=2), LDS weights ----
    {
      int r0 = base + 2 * t;
      float px[2], py[2];
      if (r0 + 2 <= N) {
        float4 v4 = *(const float4*)(pos + 2 * r0);
        px[0] = v4.x; py[0] = v4.y; px[1] = v4.z; py[1] = v4.w;
      } else {
        #pragma unroll
        for (int j = 0; j < 2; ++j) {
          int r = r0 + j;
          px[j] = (r < N) ? pos[2 * r] : 0.f;
          py[j] = (r < N) ? pos[2 * r + 1] : 0.f;
        }
      }
      float v[2][16];
      forward_rows<5, 2>(WL, px, py, v);
      #pragma unroll
      for (int j = 0; j < 2; ++j) {
        float4* row4 = (float4*)&sh[2 * t + j][0];
        row4[0] = make_float4(v[j][0],  v[j][1],  v[j][2],  v[j][3]);
        row4[1] = make_float4(v[j][4],  v[j][5],  v[j][6],  v[j][7]);
        row4[2] = make_float4(v[j][8],  v[j][9],  v[j][10], v[j][11]);
        row4[3] = make_float4(v[j][12], v[j][13], v[j][14], v[j][15]);
        sidx[2 * t + j] = (r0 + j < N) ? idx[r0 + j] : 0;
      }
    }
    __syncthreads();

    // ---- phase 2: classify + coalesced store ----
    #pragma unroll 4
    for (int k = 0; k < TROWS / 16; ++k) {
      int rb = (k << 4) + rgrp;   // row in tile; lanes 0..15 share rb
      int rg = base + rb;
      if (rg < N) {
        float4 acc = st2[sidx[rb] * 16 + chunk];
        const float4* hrow = (const float4*)&sh[rb][0];
        #pragma unroll
        for (int ii = 0; ii < 4; ++ii) {
          float4 hv = hrow[ii];   // broadcast across the 16 lanes of this row
          acc.x = fmaf(w4[ii * 4 + 0].x, hv.x, acc.x);
          acc.y = fmaf(w4[ii * 4 + 0].y, hv.x, acc.y);
          acc.z = fmaf(w4[ii * 4 + 0].z, hv.x, acc.z);
          acc.w = fmaf(w4[ii * 4 + 0].w, hv.x, acc.w);
          acc.x = fmaf(w4[ii * 4 + 1].x, hv.y, acc.x);
          acc.y = fmaf(w4[ii * 4 + 1].y, hv.y, acc.y);
          acc.z = fmaf(w4[ii * 4 + 1].z, hv.y, acc.z);
          acc.w = fmaf(w4[ii * 4 + 1].w, hv.y, acc.w);
          acc.x = fmaf(w4[ii * 4 + 2].x, hv.z, acc.x);
          acc.y = fmaf(w4[ii * 4 + 2].y, hv.z, acc.y);
          acc.z = fmaf(w4[ii * 4 + 2].z, hv.z, acc.z);
          acc.w = fmaf(w4[ii * 4 + 2].w, hv.z, acc.w);
          acc.x = fmaf(w4[ii * 4 + 3].x, hv.w, acc.x);
          acc.y = fmaf(w4[ii * 4 + 3].y, hv.w, acc.y);
          acc.z = fmaf(w4[ii * 4 + 3].z, hv.w, acc.z);
          acc.w = fmaf(w4[ii * 4 + 3].w, hv.w, acc.w);
        }
        ((float4*)(out + (size_t)rg * 64))[chunk] = acc;
      }
    }
    __syncthreads();
  }
}

extern "C" void kernel_launch(void* const* d_in, const int* in_sizes, int n_in,
                              void* d_out, int out_size, void* d_ws, size_t ws_size,
                              hipStream_t stream) {
  const float* pos = (const float*)d_in[0];
  const int*   idx = (const int*)d_in[1];
  const float* bn_g[5] = {(const float*)d_in[2], (const float*)d_in[4], (const float*)d_in[6],
                          (const float*)d_in[8], (const float*)d_in[10]};
  const float* bn_b[5] = {(const float*)d_in[3], (const float*)d_in[5], (const float*)d_in[7],
                          (const float*)d_in[9], (const float*)d_in[11]};
  const float* w[5] = {(const float*)d_in[12], (const float*)d_in[14], (const float*)d_in[16],
                       (const float*)d_in[18], (const float*)d_in[20]};
  const float* b[5] = {(const float*)d_in[13], (const float*)d_in[15], (const float*)d_in[17],
                       (const float*)d_in[19], (const float*)d_in[21]};
  const float* emb = (const float*)d_in[22];
  const float* wc  = (const float*)d_in[23];
  const float* bc  = (const float*)d_in[24];
  float* out = (float*)d_out;

  int N = in_sizes[0] / 2;
  float invN = 1.0f / (float)N;

  float* ws = (float*)d_ws;
  float* partials = ws + PARTIALS_OFF;
  float* P = ws + PARAMS_OFF;

  // bn0 stats on raw pos, fold into w1
  k_stats<0, 4><<<GRID_STATS, WG, 0, stream>>>(pos, N, P, partials);
  k_fold<<<1, WG, 0, stream>>>(partials, bn_g[0], bn_b[0], w[0], b[0], 2, 16, invN,
                               P + PW1, P + PB1);
  // bn1 stats on h, fold into w2
  k_stats<1, 4><<<GRID_STATS, WG, 0, stream>>>(pos, N, P, partials);
  k_fold<<<1, WG, 0, stream>>>(partials, bn_g[1], bn_b[1], w[1], b[1], 16, 16, invN,
                               P + PW2, P + PB2);
  // bn2 stats on y1, fold into w3
  k_stats<2, 4><<<GRID_STATS, WG, 0, stream>>>(pos, N, P, partials);
  k_fold<<<1, WG, 0, stream>>>(partials, bn_g[2], bn_b[2], w[2], b[2], 16, 16, invN,
                               P + PW3, P + PB3);
  // bn3 stats on h2, fold into w4
  k_stats<3, 2><<<GRID_STATS, WG, 0, stream>>>(pos, N, P, partials);
  k_fold<<<1, WG, 0, stream>>>(partials, bn_g[3], bn_b[3], w[3], b[3], 16, 16, invN,
                               P + PW4, P + PB4);
  // bn4 stats on y3, fold into w5
  k_stats<4, 2><<<GRID_STATS, WG, 0, stream>>>(pos, N, P, partials);
  k_fold<<<1, WG, 0, stream>>>(partials, bn_g[4], bn_b[4], w[4], b[4], 16, 16, invN,
                               P + PW5, P + PB5);
  // final: recompute chain (LDS weights, RB=2), classify, coalesced write
  k_final<<<GRID_FINAL, WG, 0, stream>>>(pos, idx, P, wc, emb, bc, out, N);
}